// Round 13
// baseline (277.884 us; speedup 1.0000x reference)
//
#include <hip/hip_runtime.h>
#include <hip/hip_bf16.h>

#define TT 2048
#define DMM 512
#define HH 8
#define DH 64
#define NBH 16   // B*H
#define UU 3     // int(0.4*ln(2048)) = 3

typedef unsigned short u16;
typedef short bf16x8 __attribute__((ext_vector_type(8)));
typedef float f32x4 __attribute__((ext_vector_type(4)));

#define NW1 262144     // per-z W elems (512*512)
#define NX1 2097152    // per-z X elems (2*2048*512)
#define NSPLIT (3*NW1 + 3*NX1)   // 7077888

// ---- ws layout (float offsets) ----
#define W_ZS     0          // [4][16][2048]
#define W_SS     131072     // [4][16][2048]
#define W_ZP     262144     // [48][4]
#define W_OP     262336     // [48][4][64]
#define W_TOPK   274624     // [48] int
#define W_U16    274688     // u16 region (byte 1098752, 16B aligned)
// u16 region: qhi,qlo,khi,klo,Vh (5*NX1... wait NPROJ=NX1) ; whi,wlo (3*NW1 each); xhi,xlo (3*NX1 each)
#define NPROJ 2097152
#define W_NEED_BYTES (274688*4 + (size_t)(5*NPROJ + 2*3*NW1 + 2*3*NX1)*2)  // ~50.4 MB

// ===========================================================================
__global__ void canary_kernel(float* __restrict__ out, float code, int n)
{
    int i = blockIdx.x * 256 + threadIdx.x;
    if (i < n) out[i] = (i == 0) ? code : 0.f;
}

__device__ __forceinline__ float rc_bf(u16 hi, u16 lo)
{
    return __uint_as_float(((unsigned)hi) << 16) + __uint_as_float(((unsigned)lo) << 16);
}

// ===========================================================================
// Stage 0: split W (3x512x512) and X (3x2x2048x512) into hi/lo u16.
// ===========================================================================
__global__ __launch_bounds__(256) void split_kernel(
    const float* __restrict__ q, const float* __restrict__ k, const float* __restrict__ v,
    const float* __restrict__ Wq, const float* __restrict__ Wk, const float* __restrict__ Wv,
    u16* __restrict__ whi, u16* __restrict__ wlo,
    u16* __restrict__ xhi, u16* __restrict__ xlo)
{
    const size_t base = ((size_t)blockIdx.x * 256 + threadIdx.x) * 4;
    if (base >= (size_t)NSPLIT) return;
    const float* src; u16 *dh, *dl;
    if (base < (size_t)3*NW1) {
        const int z = (int)(base / NW1);
        src = (z == 0 ? Wq : (z == 1 ? Wk : Wv)) + (base - (size_t)z*NW1);
        dh = whi + base; dl = wlo + base;
    } else {
        const size_t j = base - (size_t)3*NW1;
        const int z = (int)(j / NX1);
        src = (z == 0 ? q : (z == 1 ? k : v)) + (j - (size_t)z*NX1);
        dh = xhi + j; dl = xlo + j;
    }
    float4 w4 = *(const float4*)src;
    float wv4[4] = {w4.x, w4.y, w4.z, w4.w};
    unsigned hb[4], lb[4];
#pragma unroll
    for (int i = 0; i < 4; ++i) {
        unsigned u = __float_as_uint(wv4[i]);
        hb[i] = u >> 16;
        float hf = __uint_as_float(u & 0xFFFF0000u);
        lb[i] = __float_as_uint(wv4[i] - hf) >> 16;
    }
    uint2 H, L;
    H.x = hb[0] | (hb[1] << 16); H.y = hb[2] | (hb[3] << 16);
    L.x = lb[0] | (lb[1] << 16); L.y = lb[2] | (lb[3] << 16);
    *(uint2*)dh = H;
    *(uint2*)dl = L;
}

// ===========================================================================
// Stage 1 (MFMA, LDS-free): P = X @ W^T + b. Tile 64x64, 4 waves, fragments
// loaded directly from pre-split global (L1/L2-hot). No barriers.
// grid (64 row-tiles, 8 heads, 3).
// ===========================================================================
__global__ __launch_bounds__(256) void projM_kernel(
    const u16* __restrict__ xhi, const u16* __restrict__ xlo,
    const u16* __restrict__ whi, const u16* __restrict__ wlo,
    const float* __restrict__ bq, const float* __restrict__ bk, const float* __restrict__ bv,
    u16* __restrict__ qhi, u16* __restrict__ qlo,
    u16* __restrict__ khi, u16* __restrict__ klo,
    u16* __restrict__ Vh)
{
    const int z = blockIdx.z;
    const float* Bi = (z == 0) ? bq : (z == 1) ? bk : bv;
    const int tid = threadIdx.x;
    const int lane = tid & 63;
    const int m0 = blockIdx.x * 64;
    const int h  = blockIdx.y;
    const int n0 = h * 64;
    const int rw = (tid >> 6) * 16;
    const int fr = lane & 15;
    const int kg = lane >> 4;
    const int kb = kg * 8;

    const u16* axh = xhi + (size_t)z * NX1 + (size_t)(m0 + rw + fr) * DMM + kb;
    const u16* axl = xlo + (size_t)z * NX1 + (size_t)(m0 + rw + fr) * DMM + kb;
    const u16* bwh = whi + (size_t)z * NW1 + (size_t)(n0 + fr) * DMM + kb;
    const u16* bwl = wlo + (size_t)z * NW1 + (size_t)(n0 + fr) * DMM + kb;

    f32x4 acc[4];
#pragma unroll
    for (int j = 0; j < 4; ++j) acc[j] = (f32x4){0.f, 0.f, 0.f, 0.f};

#pragma unroll 2
    for (int k0 = 0; k0 < DMM; k0 += 32) {
        const bf16x8 ah = *(const bf16x8*)(axh + k0);
        const bf16x8 al = *(const bf16x8*)(axl + k0);
#pragma unroll
        for (int j = 0; j < 4; ++j) {
            const bf16x8 bhf = *(const bf16x8*)(bwh + (size_t)j*16*DMM + k0);
            const bf16x8 blf = *(const bf16x8*)(bwl + (size_t)j*16*DMM + k0);
            acc[j] = __builtin_amdgcn_mfma_f32_16x16x32_bf16(ah, bhf, acc[j], 0, 0, 0);
            acc[j] = __builtin_amdgcn_mfma_f32_16x16x32_bf16(ah, blf, acc[j], 0, 0, 0);
            acc[j] = __builtin_amdgcn_mfma_f32_16x16x32_bf16(al, bhf, acc[j], 0, 0, 0);
        }
    }

    // epilogue: D frag col = lane&15, row = (lane>>4)*4 + r
#pragma unroll
    for (int j = 0; j < 4; ++j) {
        const int d = j*16 + fr;
        const float bias = Bi[n0 + d];
#pragma unroll
        for (int r = 0; r < 4; ++r) {
            const int row = m0 + rw + kg*4 + r;
            const int bb  = row >> 11;
            const int t   = row & 2047;
            const float val = acc[j][r] + bias;
            const size_t idx = ((size_t)(bb*HH + h) * TT + t) * DH + d;
            const unsigned u = __float_as_uint(val);
            if (z == 2) {
                Vh[idx] = (u16)((u + 0x7FFFu + ((u >> 16) & 1u)) >> 16);   // RNE
            } else {
                const u16 hi = (u16)(u >> 16);
                const float hf = __uint_as_float(u & 0xFFFF0000u);
                const u16 lo = (u16)(__float_as_uint(val - hf) >> 16);
                if (z == 0) { qhi[idx] = hi; qlo[idx] = lo; }
                else        { khi[idx] = hi; klo[idx] = lo; }
            }
        }
    }
}

// ===========================================================================
// Stage 2 (MFMA, LDS-free): partial (Z,S1) per q-row over a quarter of K cols.
// grid (32 q-tiles, 16 bh, 4 quarters), 256 thr. Fragments from global.
// ===========================================================================
__global__ __launch_bounds__(256) void scoreM_kernel(
    const u16* __restrict__ qhi, const u16* __restrict__ qlo,
    const u16* __restrict__ khi, const u16* __restrict__ klo,
    float* __restrict__ zs, float* __restrict__ ss)
{
    const int qt = blockIdx.x, bh = blockIdx.y, zh = blockIdx.z;
    const int qr0 = qt * 64;
    const int tid = threadIdx.x;
    const int lane = tid & 63;
    const int rw = (tid >> 6) * 16;
    const int fr = lane & 15;
    const int kg = lane >> 4;
    const int kb = kg * 8;

    const size_t qbase = ((size_t)bh*TT + qr0 + rw + fr) * DH;
    const bf16x8 qh0 = *(const bf16x8*)(qhi + qbase + kb);
    const bf16x8 qh1 = *(const bf16x8*)(qhi + qbase + 32 + kb);
    const bf16x8 ql0 = *(const bf16x8*)(qlo + qbase + kb);
    const bf16x8 ql1 = *(const bf16x8*)(qlo + qbase + 32 + kb);

    float zl[4]  = {0.f, 0.f, 0.f, 0.f};
    float s1l[4] = {0.f, 0.f, 0.f, 0.f};

    for (int ct = zh * 8; ct < zh * 8 + 8; ++ct) {
        f32x4 acc[4];
#pragma unroll
        for (int j = 0; j < 4; ++j) acc[j] = (f32x4){0.f, 0.f, 0.f, 0.f};

        const size_t kr = ((size_t)bh*TT + ct*64 + fr) * DH;
#pragma unroll
        for (int j = 0; j < 4; ++j) {
            const u16* khp = khi + kr + (size_t)j*16*DH;
            const u16* klp = klo + kr + (size_t)j*16*DH;
            const bf16x8 b0h = *(const bf16x8*)(khp + kb);
            const bf16x8 b0l = *(const bf16x8*)(klp + kb);
            acc[j] = __builtin_amdgcn_mfma_f32_16x16x32_bf16(qh0, b0h, acc[j], 0, 0, 0);
            acc[j] = __builtin_amdgcn_mfma_f32_16x16x32_bf16(qh0, b0l, acc[j], 0, 0, 0);
            acc[j] = __builtin_amdgcn_mfma_f32_16x16x32_bf16(ql0, b0h, acc[j], 0, 0, 0);
            const bf16x8 b1h = *(const bf16x8*)(khp + 32 + kb);
            const bf16x8 b1l = *(const bf16x8*)(klp + 32 + kb);
            acc[j] = __builtin_amdgcn_mfma_f32_16x16x32_bf16(qh1, b1h, acc[j], 0, 0, 0);
            acc[j] = __builtin_amdgcn_mfma_f32_16x16x32_bf16(qh1, b1l, acc[j], 0, 0, 0);
            acc[j] = __builtin_amdgcn_mfma_f32_16x16x32_bf16(ql1, b1h, acc[j], 0, 0, 0);
        }

#pragma unroll
        for (int j = 0; j < 4; ++j) {
#pragma unroll
            for (int r = 0; r < 4; ++r) {
                float s = acc[j][r] * 0.125f;
                float e = __expf(s);
                zl[r]  += e;
                s1l[r] += e * s;
            }
        }
    }

    // butterfly over the 16 fr-lanes sharing kg
#pragma unroll
    for (int off = 1; off < 16; off <<= 1) {
#pragma unroll
        for (int r = 0; r < 4; ++r) {
            zl[r]  += __shfl_xor(zl[r],  off, 64);
            s1l[r] += __shfl_xor(s1l[r], off, 64);
        }
    }

    if (fr == 0) {
#pragma unroll
        for (int r = 0; r < 4; ++r) {
            const int row = qr0 + rw + kg*4 + r;
            const size_t o = ((size_t)zh * NBH + bh) * TT + row;
            zs[o] = zl[r];
            ss[o] = s1l[r];
        }
    }
}

// ===========================================================================
// Stage 3: grid (48 bu, 4 col-parts). Each block: merge partials -> KL,
// iterative argmax (redundant per part, deterministic identical), then
// reduced-attention PARTIAL over its 512 columns. No atomics.
// ===========================================================================
__global__ __launch_bounds__(256) void top3red_kernel(
    const float* __restrict__ zs, const float* __restrict__ ss,
    const u16* __restrict__ qhi, const u16* __restrict__ qlo,
    const u16* __restrict__ khi, const u16* __restrict__ klo,
    const u16* __restrict__ Vh,
    int* __restrict__ topk, float* __restrict__ zp_out, float* __restrict__ op_out)
{
    __shared__ float kv[TT];
    __shared__ float pv[4];
    __shared__ int   pi[4];
    __shared__ int   tsel_sh;
    __shared__ float qs[DH];
    __shared__ float wbuf[512];
    __shared__ float red4[4][DH];
    __shared__ float wz[4];

    const int bu = blockIdx.x;      // 0..47
    const int part = blockIdx.y;    // 0..3
    const int bh = bu / UU;
    const int uu = bu - bh * UU;
    const int tid = threadIdx.x;
    const int wv = tid >> 6;

    // ---- phase A: KL from partials + iterative argmax (ties -> low idx) ----
    for (int i = tid; i < TT; i += 256) {
        float Z = 0.f, S = 0.f;
#pragma unroll
        for (int p = 0; p < 4; ++p) {
            const size_t o = ((size_t)p * NBH + bh) * TT + i;
            Z += zs[o];
            S += ss[o];
        }
        kv[i] = S / Z - logf(Z);   // -log_u constant: argmax-invariant
    }
    __syncthreads();
    for (int it = 0; it <= uu; ++it) {
        float bvv = -3e38f; int bi = TT;
        for (int i = tid; i < TT; i += 256) {
            float vv = kv[i];
            if (vv > bvv) { bvv = vv; bi = i; }
        }
#pragma unroll
        for (int off = 1; off < 64; off <<= 1) {
            float ov = __shfl_xor(bvv, off, 64);
            int   oi = __shfl_xor(bi, off, 64);
            if (ov > bvv || (ov == bvv && oi < bi)) { bvv = ov; bi = oi; }
        }
        if ((tid & 63) == 0) { pv[wv] = bvv; pi[wv] = bi; }
        __syncthreads();
        if (tid == 0) {
            float Bv = pv[0]; int Bi2 = pi[0];
#pragma unroll
            for (int w2 = 1; w2 < 4; ++w2) {
                if (pv[w2] > Bv || (pv[w2] == Bv && pi[w2] < Bi2)) { Bv = pv[w2]; Bi2 = pi[w2]; }
            }
            tsel_sh = Bi2;
            kv[Bi2] = -3e38f;
        }
        __syncthreads();
    }
    const int tsel = tsel_sh;
    if (tid == 0 && part == 0) topk[bu] = tsel;

    // ---- phase B: reduced-attention partial over cols [part*512, +512) ----
    if (tid < DH) {
        const size_t qi = ((size_t)bh*TT + tsel) * DH + tid;
        qs[tid] = rc_bf(qhi[qi], qlo[qi]);
    }
    __syncthreads();

    const int c0 = part * 512;
    float zp = 0.f;
    for (int ii = tid; ii < 512; ii += 256) {
        const int cc = c0 + ii;
        const u16* kh  = khi + ((size_t)bh*TT + cc) * DH;
        const u16* kl_ = klo + ((size_t)bh*TT + cc) * DH;
        float s = 0.f;
#pragma unroll
        for (int d8 = 0; d8 < DH; d8 += 8) {
            uint4 H = *(const uint4*)(kh + d8);
            uint4 L = *(const uint4*)(kl_ + d8);
            const unsigned hw[4] = {H.x, H.y, H.z, H.w};
            const unsigned lw[4] = {L.x, L.y, L.z, L.w};
#pragma unroll
            for (int i = 0; i < 4; ++i) {
                float k0 = __uint_as_float(hw[i] << 16) + __uint_as_float(lw[i] << 16);
                float k1 = __uint_as_float(hw[i] & 0xFFFF0000u) + __uint_as_float(lw[i] & 0xFFFF0000u);
                s += qs[d8 + i*2]     * k0;
                s += qs[d8 + i*2 + 1] * k1;
            }
        }
        s *= 0.125f;
        s = fminf(fmaxf(s, -10000.f), 10000.f);
        float e = __expf(s);
        wbuf[ii] = e;
        zp += e;
    }
#pragma unroll
    for (int off = 1; off < 64; off <<= 1) zp += __shfl_xor(zp, off, 64);
    if ((tid & 63) == 0) wz[wv] = zp;
    __syncthreads();
    if (tid == 0) zp_out[bu*4 + part] = wz[0] + wz[1] + wz[2] + wz[3];

    const int d = tid & 63, cq = tid >> 6;
    float o = 0.f;
    for (int ii = cq * 128; ii < cq * 128 + 128; ++ii) {
        const u16 vb = Vh[((size_t)bh*TT + c0 + ii) * DH + d];
        o += wbuf[ii] * __uint_as_float(((unsigned)vb) << 16);
    }
    red4[cq][d] = o;
    __syncthreads();
    if (tid < DH)
        op_out[(size_t)(bu*4 + part) * DH + tid] =
            red4[0][tid] + red4[1][tid] + red4[2][tid] + red4[3][tid];
}

// ===========================================================================
// Stage 4: out[b,t,:] = bo + sum_{(h,u): topk==t} (merge partials) @ Wo^T
// ===========================================================================
__global__ __launch_bounds__(256) void outU_kernel(
    const float* __restrict__ zp, const float* __restrict__ op,
    const int* __restrict__ topk,
    const float* __restrict__ Wo, const float* __restrict__ bo,
    float* __restrict__ out)
{
    const int blk = blockIdx.x;
    const int b   = blk >> 11;
    const int t   = blk & 2047;
    const int tid = threadIdx.x;
    float acc0 = bo[tid];
    float acc1 = bo[tid + 256];
    for (int h = 0; h < HH; ++h) {
#pragma unroll
        for (int u = 0; u < UU; ++u) {
            const int idx = (b*HH + h)*UU + u;
            if (topk[idx] == t) {
                const float Z = zp[idx*4] + zp[idx*4+1] + zp[idx*4+2] + zp[idx*4+3];
                const float invz = 1.0f / Z;
                const float* o0 = op + (size_t)(idx*4)     * DH;
                const float* o1 = op + (size_t)(idx*4 + 1) * DH;
                const float* o2 = op + (size_t)(idx*4 + 2) * DH;
                const float* o3 = op + (size_t)(idx*4 + 3) * DH;
                const float* w0 = Wo + (size_t)tid * DMM + h*DH;
                const float* w1 = Wo + (size_t)(tid + 256) * DMM + h*DH;
#pragma unroll
                for (int dd = 0; dd < DH; ++dd) {
                    const float rv = (o0[dd] + o1[dd] + o2[dd] + o3[dd]) * invz;
                    acc0 += rv * w0[dd];
                    acc1 += rv * w1[dd];
                }
            }
        }
    }
    out[(size_t)blk * DMM + tid]       = acc0;
    out[(size_t)blk * DMM + tid + 256] = acc1;
}

// ===========================================================================
extern "C" void kernel_launch(void* const* d_in, const int* in_sizes, int n_in,
                              void* d_out, int out_size, void* d_ws, size_t ws_size,
                              hipStream_t stream)
{
    float* out = (float*)d_out;
    const int nblk = (out_size + 255) / 256;

    if (n_in != 11) {
        canary_kernel<<<nblk, 256, 0, stream>>>(out, 9216.f + 8.f * (float)n_in, out_size);
        return;
    }
    const int s0 = in_sizes[0];
    int mode = -1;
    if ((s0 == 2097152 || s0 == 8388608) &&
        (in_sizes[4] == 512 || in_sizes[4] == 2048)) mode = 0;
    else if ((s0 == 262144 || s0 == 1048576) &&
             (in_sizes[8] == 2097152 || in_sizes[8] == 8388608)) mode = 1;
    if (mode < 0) {
        canary_kernel<<<nblk, 256, 0, stream>>>(out, 8192.f, out_size);
        return;
    }
    if (ws_size < (size_t)W_NEED_BYTES) {
        canary_kernel<<<nblk, 256, 0, stream>>>(out, 5120.f, out_size);
        return;
    }

    const float *q, *k, *v, *Wq, *bq, *Wk, *bk, *Wv, *bv, *Wo, *bo;
    if (mode == 0) {
        q  = (const float*)d_in[0];  k  = (const float*)d_in[1];
        v  = (const float*)d_in[2];  Wq = (const float*)d_in[3];
        bq = (const float*)d_in[4];  Wk = (const float*)d_in[5];
        bk = (const float*)d_in[6];  Wv = (const float*)d_in[7];
        bv = (const float*)d_in[8];  Wo = (const float*)d_in[9];
        bo = (const float*)d_in[10];
    } else {
        Wk = (const float*)d_in[0];  Wo = (const float*)d_in[1];
        Wq = (const float*)d_in[2];  Wv = (const float*)d_in[3];
        bk = (const float*)d_in[4];  bo = (const float*)d_in[5];
        bq = (const float*)d_in[6];  bv = (const float*)d_in[7];
        k  = (const float*)d_in[8];  q  = (const float*)d_in[9];
        v  = (const float*)d_in[10];
    }

    float* ws     = (float*)d_ws;
    float* zs     = ws + W_ZS;
    float* ss     = ws + W_SS;
    float* zp     = ws + W_ZP;
    float* op     = ws + W_OP;
    int*   topk   = (int*)(ws + W_TOPK);
    u16*   qhi    = (u16*)(ws + W_U16);
    u16*   qlo    = qhi + (size_t)NPROJ;
    u16*   khi    = qlo + (size_t)NPROJ;
    u16*   klo    = khi + (size_t)NPROJ;
    u16*   Vh     = klo + (size_t)NPROJ;
    u16*   whi    = Vh  + (size_t)NPROJ;
    u16*   wlo    = whi + (size_t)(3*NW1);
    u16*   xhi    = wlo + (size_t)(3*NW1);
    u16*   xlo    = xhi + (size_t)(3*NX1);

    split_kernel<<<(NSPLIT/4 + 255)/256, 256, 0, stream>>>(q, k, v, Wq, Wk, Wv,
                                                           whi, wlo, xhi, xlo);
    projM_kernel<<<dim3(64, 8, 3), 256, 0, stream>>>(xhi, xlo, whi, wlo, bq, bk, bv,
                                                     qhi, qlo, khi, klo, Vh);
    scoreM_kernel<<<dim3(32, 16, 4), 256, 0, stream>>>(qhi, qlo, khi, klo, zs, ss);
    top3red_kernel<<<dim3(48, 4), 256, 0, stream>>>(zs, ss, qhi, qlo, khi, klo, Vh,
                                                    topk, zp, op);
    outU_kernel<<<4096, 256, 0, stream>>>(zp, op, topk, Wo, bo, out);
}

// Round 14
// 162.643 us; speedup vs baseline: 1.7086x; 1.7086x over previous
//
#include <hip/hip_runtime.h>
#include <hip/hip_bf16.h>

#define TT 2048
#define DMM 512
#define HH 8
#define DH 64
#define NBH 16   // B*H
#define UU 3     // int(0.4*ln(2048)) = 3

typedef unsigned short u16;
typedef short bf16x8 __attribute__((ext_vector_type(8)));
typedef float f32x4 __attribute__((ext_vector_type(4)));

// ---- ws layout (float offsets) ----
#define W_ZS     0          // [4][16][2048] f32 partial Z
#define W_SS     131072     // [4][16][2048] f32 partial S1
#define W_OUTRED 262144     // [48][64] f32 (normalized)
#define W_TOPK   265216     // [48] int
#define W_U16    265280     // u16 region starts (16B aligned)
#define NPROJ 2097152
#define NW    786432
#define W_NEED_BYTES (265280*4 + 5*NPROJ*2 + 2*NW*2)

// ===========================================================================
__global__ void canary_kernel(float* __restrict__ out, float code, int n)
{
    int i = blockIdx.x * 256 + threadIdx.x;
    if (i < n) out[i] = (i == 0) ? code : 0.f;
}

__device__ __forceinline__ float rc_bf(u16 hi, u16 lo)
{
    return __uint_as_float(((unsigned)hi) << 16) + __uint_as_float(((unsigned)lo) << 16);
}

// ===========================================================================
// Stage 0: pre-split Wq,Wk,Wv -> hi/lo u16 arrays [3][512][512]
// ===========================================================================
__global__ __launch_bounds__(256) void wsplit_kernel(
    const float* __restrict__ Wq, const float* __restrict__ Wk,
    const float* __restrict__ Wv,
    u16* __restrict__ whi, u16* __restrict__ wlo)
{
    const int n1 = DMM * DMM;
    for (int i = blockIdx.x * 256 + threadIdx.x; i < 3 * n1; i += gridDim.x * 256) {
        const int z = i / n1, rem = i - z * n1;
        const float w = (z == 0 ? Wq : (z == 1 ? Wk : Wv))[rem];
        const unsigned u = __float_as_uint(w);
        const u16 hi = (u16)(u >> 16);
        const float hf = __uint_as_float(u & 0xFFFF0000u);
        whi[i] = hi;
        wlo[i] = (u16)(__float_as_uint(w - hf) >> 16);
    }
}

// ===========================================================================
// Stage 1 (MFMA): P = X @ W^T + b. Tile 64 rows x 64 cols, BK=32.
// 128 thr = 2 waves; each wave owns 32 rows (2 row-frags) -> B tile read
// once per 32 output rows (vs once per 16 at 4 waves). LDS 20 KB.
// grid (64 row-tiles, 8 heads, 3).
// ===========================================================================
__global__ __launch_bounds__(128) void projM_kernel(
    const float* __restrict__ q, const float* __restrict__ k, const float* __restrict__ v,
    const u16* __restrict__ whi, const u16* __restrict__ wlo,
    const float* __restrict__ bq, const float* __restrict__ bk, const float* __restrict__ bv,
    u16* __restrict__ qhi, u16* __restrict__ qlo,
    u16* __restrict__ khi, u16* __restrict__ klo,
    u16* __restrict__ Vh)
{
    __shared__ u16 Ah[64][40], Al[64][40], Bh[64][40], Bl[64][40];

    const int z = blockIdx.z;
    const float *X, *Bi;
    if (z == 0)      { X = q; Bi = bq; }
    else if (z == 1) { X = k; Bi = bk; }
    else             { X = v; Bi = bv; }

    const int tid = threadIdx.x;
    const int m0 = blockIdx.x * 64;
    const int h  = blockIdx.y;
    const int n0 = h * 64;
    const int w  = tid >> 6;          // wave 0/1 -> rows w*32..+31
    const int lane = tid & 63;
    const int fr = lane & 15;
    const int kg = lane >> 4;
    const int kb = kg * 8;

    const int sr = tid >> 1;          // staging row 0..63
    const int sk = (tid & 1) * 16;    // staging k 0/16

    f32x4 acc[2][4];
#pragma unroll
    for (int t = 0; t < 2; ++t)
#pragma unroll
        for (int j = 0; j < 4; ++j) acc[t][j] = (f32x4){0.f, 0.f, 0.f, 0.f};

    for (int k0 = 0; k0 < DMM; k0 += 32) {
        __syncthreads();
        {
            // X rows: 16 floats -> split hi/lo
            const float* p = X + (size_t)(m0 + sr) * DMM + k0 + sk;
            float xv[16];
#pragma unroll
            for (int i4 = 0; i4 < 4; ++i4) {
                float4 a = *(const float4*)(p + i4 * 4);
                xv[i4*4+0]=a.x; xv[i4*4+1]=a.y; xv[i4*4+2]=a.z; xv[i4*4+3]=a.w;
            }
            unsigned hb[16], lb[16];
#pragma unroll
            for (int i = 0; i < 16; ++i) {
                unsigned u = __float_as_uint(xv[i]);
                hb[i] = u >> 16;
                float hf = __uint_as_float(u & 0xFFFF0000u);
                lb[i] = __float_as_uint(xv[i] - hf) >> 16;
            }
#pragma unroll
            for (int half = 0; half < 2; ++half) {
                uint4 H, L;
                H.x = hb[half*8+0]|(hb[half*8+1]<<16); H.y = hb[half*8+2]|(hb[half*8+3]<<16);
                H.z = hb[half*8+4]|(hb[half*8+5]<<16); H.w = hb[half*8+6]|(hb[half*8+7]<<16);
                L.x = lb[half*8+0]|(lb[half*8+1]<<16); L.y = lb[half*8+2]|(lb[half*8+3]<<16);
                L.z = lb[half*8+4]|(lb[half*8+5]<<16); L.w = lb[half*8+6]|(lb[half*8+7]<<16);
                *(uint4*)&Ah[sr][sk + half*8] = H;
                *(uint4*)&Al[sr][sk + half*8] = L;
            }

            // W rows: pre-split copy (16 u16 = 2 uint4 each)
            const size_t wi = ((size_t)z * DMM + n0 + sr) * DMM + k0 + sk;
            *(uint4*)&Bh[sr][sk]     = *(const uint4*)(whi + wi);
            *(uint4*)&Bh[sr][sk + 8] = *(const uint4*)(whi + wi + 8);
            *(uint4*)&Bl[sr][sk]     = *(const uint4*)(wlo + wi);
            *(uint4*)&Bl[sr][sk + 8] = *(const uint4*)(wlo + wi + 8);
        }
        __syncthreads();

        bf16x8 ah[2], al[2];
#pragma unroll
        for (int t = 0; t < 2; ++t) {
            ah[t] = *(const bf16x8*)&Ah[w*32 + t*16 + fr][kb];
            al[t] = *(const bf16x8*)&Al[w*32 + t*16 + fr][kb];
        }
#pragma unroll
        for (int j = 0; j < 4; ++j) {
            bf16x8 bhf = *(const bf16x8*)&Bh[j*16 + fr][kb];
            bf16x8 blf = *(const bf16x8*)&Bl[j*16 + fr][kb];
#pragma unroll
            for (int t = 0; t < 2; ++t) {
                acc[t][j] = __builtin_amdgcn_mfma_f32_16x16x32_bf16(ah[t], bhf, acc[t][j], 0, 0, 0);
                acc[t][j] = __builtin_amdgcn_mfma_f32_16x16x32_bf16(ah[t], blf, acc[t][j], 0, 0, 0);
                acc[t][j] = __builtin_amdgcn_mfma_f32_16x16x32_bf16(al[t], bhf, acc[t][j], 0, 0, 0);
            }
        }
    }

    // epilogue: D frag col = lane&15, row = (lane>>4)*4 + r
#pragma unroll
    for (int t = 0; t < 2; ++t) {
#pragma unroll
        for (int j = 0; j < 4; ++j) {
            const int d = j*16 + fr;
            const float bias = Bi[n0 + d];
#pragma unroll
            for (int r = 0; r < 4; ++r) {
                const int row = m0 + w*32 + t*16 + kg*4 + r;
                const int bb  = row >> 11;
                const int tt  = row & 2047;
                const float val = acc[t][j][r] + bias;
                const size_t idx = ((size_t)(bb*HH + h) * TT + tt) * DH + d;
                const unsigned u = __float_as_uint(val);
                if (z == 2) {
                    Vh[idx] = (u16)((u + 0x7FFFu + ((u >> 16) & 1u)) >> 16);   // RNE
                } else {
                    const u16 hi = (u16)(u >> 16);
                    const float hf = __uint_as_float(u & 0xFFFF0000u);
                    const u16 lo = (u16)(__float_as_uint(val - hf) >> 16);
                    if (z == 0) { qhi[idx] = hi; qlo[idx] = lo; }
                    else        { khi[idx] = hi; klo[idx] = lo; }
                }
            }
        }
    }
}

// ===========================================================================
// Stage 2 (MFMA): partial (Z,S1) per q-row over a quarter of the K columns.
// grid (32 q-tiles, 16 bh, 4 quarters), 128 thr = 2 waves; each wave 32 rows
// (2 row-frags) -> K tile read once per 32 rows. LDS 19.4 KB -> 8 blocks/CU.
// ===========================================================================
__global__ __launch_bounds__(128) void scoreM_kernel(
    const u16* __restrict__ qhi, const u16* __restrict__ qlo,
    const u16* __restrict__ khi, const u16* __restrict__ klo,
    float* __restrict__ zs, float* __restrict__ ss)
{
    __shared__ u16 Kh[64][76], Kl[64][76];

    const int qt = blockIdx.x, bh = blockIdx.y, zh = blockIdx.z;
    const int qr0 = qt * 64;
    const int tid = threadIdx.x;
    const int w  = tid >> 6;
    const int lane = tid & 63;
    const int fr = lane & 15;
    const int kg = lane >> 4;
    const int kb = kg * 8;

    // Q fragments direct to registers (2 row-frags per wave)
    bf16x8 qh0[2], qh1[2], ql0[2], ql1[2];
#pragma unroll
    for (int t = 0; t < 2; ++t) {
        const size_t qbase = ((size_t)bh*TT + qr0 + w*32 + t*16 + fr) * DH;
        qh0[t] = *(const bf16x8*)(qhi + qbase + kb);
        qh1[t] = *(const bf16x8*)(qhi + qbase + 32 + kb);
        ql0[t] = *(const bf16x8*)(qlo + qbase + kb);
        ql1[t] = *(const bf16x8*)(qlo + qbase + 32 + kb);
    }

    float zl[2][4], s1l[2][4];
#pragma unroll
    for (int t = 0; t < 2; ++t)
#pragma unroll
        for (int r = 0; r < 4; ++r) { zl[t][r] = 0.f; s1l[t][r] = 0.f; }

    const int c  = tid >> 1;          // 0..63
    const int dq = (tid & 1) * 32;    // 0/32

    for (int ct = zh * 8; ct < zh * 8 + 8; ++ct) {   // 64-col tiles
        __syncthreads();
        {
            const u16* sh = khi + ((size_t)bh*TT + ct*64 + c) * DH + dq;
            const u16* sl = klo + ((size_t)bh*TT + ct*64 + c) * DH + dq;
#pragma unroll
            for (int i = 0; i < 4; ++i) {
                *(uint4*)&Kh[c][dq + i*8] = *(const uint4*)(sh + i*8);
                *(uint4*)&Kl[c][dq + i*8] = *(const uint4*)(sl + i*8);
            }
        }
        __syncthreads();

        f32x4 acc[2][4];
#pragma unroll
        for (int t = 0; t < 2; ++t)
#pragma unroll
            for (int j = 0; j < 4; ++j) acc[t][j] = (f32x4){0.f, 0.f, 0.f, 0.f};

#pragma unroll
        for (int j = 0; j < 4; ++j) {
            const bf16x8 b0h = *(const bf16x8*)&Kh[j*16 + fr][kb];
            const bf16x8 b0l = *(const bf16x8*)&Kl[j*16 + fr][kb];
            const bf16x8 b1h = *(const bf16x8*)&Kh[j*16 + fr][32 + kb];
            const bf16x8 b1l = *(const bf16x8*)&Kl[j*16 + fr][32 + kb];
#pragma unroll
            for (int t = 0; t < 2; ++t) {
                acc[t][j] = __builtin_amdgcn_mfma_f32_16x16x32_bf16(qh0[t], b0h, acc[t][j], 0, 0, 0);
                acc[t][j] = __builtin_amdgcn_mfma_f32_16x16x32_bf16(qh0[t], b0l, acc[t][j], 0, 0, 0);
                acc[t][j] = __builtin_amdgcn_mfma_f32_16x16x32_bf16(ql0[t], b0h, acc[t][j], 0, 0, 0);
                acc[t][j] = __builtin_amdgcn_mfma_f32_16x16x32_bf16(qh1[t], b1h, acc[t][j], 0, 0, 0);
                acc[t][j] = __builtin_amdgcn_mfma_f32_16x16x32_bf16(qh1[t], b1l, acc[t][j], 0, 0, 0);
                acc[t][j] = __builtin_amdgcn_mfma_f32_16x16x32_bf16(ql1[t], b1h, acc[t][j], 0, 0, 0);
            }
        }

#pragma unroll
        for (int t = 0; t < 2; ++t) {
#pragma unroll
            for (int j = 0; j < 4; ++j) {
#pragma unroll
                for (int r = 0; r < 4; ++r) {
                    float s = acc[t][j][r] * 0.125f;
                    float e = __expf(s);
                    zl[t][r]  += e;
                    s1l[t][r] += e * s;
                }
            }
        }
    }

    // butterfly over the 16 fr-lanes sharing kg
#pragma unroll
    for (int off = 1; off < 16; off <<= 1) {
#pragma unroll
        for (int t = 0; t < 2; ++t)
#pragma unroll
            for (int r = 0; r < 4; ++r) {
                zl[t][r]  += __shfl_xor(zl[t][r],  off, 64);
                s1l[t][r] += __shfl_xor(s1l[t][r], off, 64);
            }
    }

    if (fr == 0) {
#pragma unroll
        for (int t = 0; t < 2; ++t)
#pragma unroll
            for (int r = 0; r < 4; ++r) {
                const int row = qr0 + w*32 + t*16 + kg*4 + r;
                const size_t o = ((size_t)zh * NBH + bh) * TT + row;
                zs[o] = zl[t][r];
                ss[o] = s1l[t][r];
            }
    }
}

// ===========================================================================
// Stage 3: one block per (bh,u). Merge 4 partials -> KL, iterative argmax,
// then reduced attention with 256 threads. (verbatim R12)
// ===========================================================================
__global__ __launch_bounds__(256) void top3redM_kernel(
    const float* __restrict__ zs, const float* __restrict__ ss,
    const u16* __restrict__ qhi, const u16* __restrict__ qlo,
    const u16* __restrict__ khi, const u16* __restrict__ klo,
    const u16* __restrict__ Vh,
    int* __restrict__ topk, float* __restrict__ outred)
{
    __shared__ float kv[TT];
    __shared__ float pv[4];
    __shared__ int   pi[4];
    __shared__ int   tsel_sh;
    __shared__ float qs[DH];
    __shared__ float wbuf[TT];
    __shared__ float red4[4][DH];
    __shared__ float wz[4];

    const int bu = blockIdx.x;      // 0..47
    const int bh = bu / UU;
    const int uu = bu - bh * UU;
    const int tid = threadIdx.x;
    const int wv = tid >> 6;

    for (int i = tid; i < TT; i += 256) {
        float Z = 0.f, S = 0.f;
#pragma unroll
        for (int p = 0; p < 4; ++p) {
            const size_t o = ((size_t)p * NBH + bh) * TT + i;
            Z += zs[o];
            S += ss[o];
        }
        kv[i] = S / Z - logf(Z);
    }
    __syncthreads();
    for (int it = 0; it <= uu; ++it) {
        float bvv = -3e38f; int bi = TT;
        for (int i = tid; i < TT; i += 256) {
            float vv = kv[i];
            if (vv > bvv) { bvv = vv; bi = i; }
        }
#pragma unroll
        for (int off = 1; off < 64; off <<= 1) {
            float ov = __shfl_xor(bvv, off, 64);
            int   oi = __shfl_xor(bi, off, 64);
            if (ov > bvv || (ov == bvv && oi < bi)) { bvv = ov; bi = oi; }
        }
        if ((tid & 63) == 0) { pv[wv] = bvv; pi[wv] = bi; }
        __syncthreads();
        if (tid == 0) {
            float Bv = pv[0]; int Bi2 = pi[0];
#pragma unroll
            for (int w2 = 1; w2 < 4; ++w2) {
                if (pv[w2] > Bv || (pv[w2] == Bv && pi[w2] < Bi2)) { Bv = pv[w2]; Bi2 = pi[w2]; }
            }
            tsel_sh = Bi2;
            kv[Bi2] = -3e38f;
        }
        __syncthreads();
    }
    const int tsel = tsel_sh;
    if (tid == 0) topk[bu] = tsel;

    if (tid < DH) {
        const size_t qi = ((size_t)bh*TT + tsel) * DH + tid;
        qs[tid] = rc_bf(qhi[qi], qlo[qi]);
    }
    __syncthreads();

    float zp = 0.f;
    for (int cc = tid; cc < TT; cc += 256) {
        const u16* kh  = khi + ((size_t)bh*TT + cc) * DH;
        const u16* kl_ = klo + ((size_t)bh*TT + cc) * DH;
        float s = 0.f;
#pragma unroll
        for (int d8 = 0; d8 < DH; d8 += 8) {
            uint4 H = *(const uint4*)(kh + d8);
            uint4 L = *(const uint4*)(kl_ + d8);
            const unsigned hw[4] = {H.x, H.y, H.z, H.w};
            const unsigned lw[4] = {L.x, L.y, L.z, L.w};
#pragma unroll
            for (int i = 0; i < 4; ++i) {
                float k0 = __uint_as_float(hw[i] << 16) + __uint_as_float(lw[i] << 16);
                float k1 = __uint_as_float(hw[i] & 0xFFFF0000u) + __uint_as_float(lw[i] & 0xFFFF0000u);
                s += qs[d8 + i*2]     * k0;
                s += qs[d8 + i*2 + 1] * k1;
            }
        }
        s *= 0.125f;
        s = fminf(fmaxf(s, -10000.f), 10000.f);
        float e = __expf(s);
        wbuf[cc] = e;
        zp += e;
    }
#pragma unroll
    for (int off = 1; off < 64; off <<= 1) zp += __shfl_xor(zp, off, 64);
    if ((tid & 63) == 0) wz[wv] = zp;
    __syncthreads();
    const float Z = wz[0] + wz[1] + wz[2] + wz[3];

    const int d = tid & 63, cq = tid >> 6;
    float o = 0.f;
    for (int cc = cq * 512; cc < cq * 512 + 512; ++cc) {
        const u16 vb = Vh[((size_t)bh*TT + cc) * DH + d];
        o += wbuf[cc] * __uint_as_float(((unsigned)vb) << 16);
    }
    red4[cq][d] = o;
    __syncthreads();
    if (tid < DH)
        outred[bu*DH + tid] =
            (red4[0][tid] + red4[1][tid] + red4[2][tid] + red4[3][tid]) / Z;
}

// ===========================================================================
// Stage 4: out[b,t,:] = bo + sum_{(h,u): topk==t} outred @ Wo[:,h*64..]^T
// (verbatim R12)
// ===========================================================================
__global__ __launch_bounds__(256) void outU_kernel(
    const float* __restrict__ outred, const int* __restrict__ topk,
    const float* __restrict__ Wo, const float* __restrict__ bo,
    float* __restrict__ out)
{
    const int blk = blockIdx.x;
    const int b   = blk >> 11;
    const int t   = blk & 2047;
    const int tid = threadIdx.x;
    float acc0 = bo[tid];
    float acc1 = bo[tid + 256];
    for (int h = 0; h < HH; ++h) {
#pragma unroll
        for (int u = 0; u < UU; ++u) {
            const int idx = (b*HH + h)*UU + u;
            if (topk[idx] == t) {
                const float* r  = outred + (size_t)idx * DH;
                const float* w0 = Wo + (size_t)tid * DMM + h*DH;
                const float* w1 = Wo + (size_t)(tid + 256) * DMM + h*DH;
#pragma unroll
                for (int dd = 0; dd < DH; ++dd) {
                    const float rv = r[dd];
                    acc0 += rv * w0[dd];
                    acc1 += rv * w1[dd];
                }
            }
        }
    }
    out[(size_t)blk * DMM + tid]       = acc0;
    out[(size_t)blk * DMM + tid + 256] = acc1;
}

// ===========================================================================
extern "C" void kernel_launch(void* const* d_in, const int* in_sizes, int n_in,
                              void* d_out, int out_size, void* d_ws, size_t ws_size,
                              hipStream_t stream)
{
    float* out = (float*)d_out;
    const int nblk = (out_size + 255) / 256;

    if (n_in != 11) {
        canary_kernel<<<nblk, 256, 0, stream>>>(out, 9216.f + 8.f * (float)n_in, out_size);
        return;
    }
    const int s0 = in_sizes[0];
    int mode = -1;
    if ((s0 == 2097152 || s0 == 8388608) &&
        (in_sizes[4] == 512 || in_sizes[4] == 2048)) mode = 0;
    else if ((s0 == 262144 || s0 == 1048576) &&
             (in_sizes[8] == 2097152 || in_sizes[8] == 8388608)) mode = 1;
    if (mode < 0) {
        canary_kernel<<<nblk, 256, 0, stream>>>(out, 8192.f, out_size);
        return;
    }
    if (ws_size < (size_t)W_NEED_BYTES) {
        canary_kernel<<<nblk, 256, 0, stream>>>(out, 5120.f, out_size);
        return;
    }

    const float *q, *k, *v, *Wq, *bq, *Wk, *bk, *Wv, *bv, *Wo, *bo;
    if (mode == 0) {
        q  = (const float*)d_in[0];  k  = (const float*)d_in[1];
        v  = (const float*)d_in[2];  Wq = (const float*)d_in[3];
        bq = (const float*)d_in[4];  Wk = (const float*)d_in[5];
        bk = (const float*)d_in[6];  Wv = (const float*)d_in[7];
        bv = (const float*)d_in[8];  Wo = (const float*)d_in[9];
        bo = (const float*)d_in[10];
    } else {
        Wk = (const float*)d_in[0];  Wo = (const float*)d_in[1];
        Wq = (const float*)d_in[2];  Wv = (const float*)d_in[3];
        bk = (const float*)d_in[4];  bo = (const float*)d_in[5];
        bq = (const float*)d_in[6];  bv = (const float*)d_in[7];
        k  = (const float*)d_in[8];  q  = (const float*)d_in[9];
        v  = (const float*)d_in[10];
    }

    float* ws     = (float*)d_ws;
    float* zs     = ws + W_ZS;
    float* ss     = ws + W_SS;
    float* outred = ws + W_OUTRED;
    int*   topk   = (int*)(ws + W_TOPK);
    u16*   qhi    = (u16*)(ws + W_U16);
    u16*   qlo    = qhi + (size_t)NPROJ;
    u16*   khi    = qlo + (size_t)NPROJ;
    u16*   klo    = khi + (size_t)NPROJ;
    u16*   Vh     = klo + (size_t)NPROJ;
    u16*   whi    = Vh  + (size_t)NPROJ;
    u16*   wlo    = whi + (size_t)NW;

    wsplit_kernel<<<1024, 256, 0, stream>>>(Wq, Wk, Wv, whi, wlo);
    projM_kernel<<<dim3(64, 8, 3), 128, 0, stream>>>(q, k, v, whi, wlo, bq, bk, bv,
                                                     qhi, qlo, khi, klo, Vh);
    scoreM_kernel<<<dim3(32, 16, 4), 128, 0, stream>>>(qhi, qlo, khi, klo, zs, ss);
    top3redM_kernel<<<48, 256, 0, stream>>>(zs, ss, qhi, qlo, khi, klo, Vh, topk, outred);
    outU_kernel<<<4096, 256, 0, stream>>>(outred, topk, Wo, bo, out);
}

// Round 15
// 133.375 us; speedup vs baseline: 2.0835x; 1.2194x over previous
//
#include <hip/hip_runtime.h>
#include <hip/hip_bf16.h>

#define TT 2048
#define DMM 512
#define HH 8
#define DH 64
#define NBH 16   // B*H
#define UU 3     // int(0.4*ln(2048)) = 3

typedef unsigned short u16;
typedef short bf16x8 __attribute__((ext_vector_type(8)));
typedef float f32x4 __attribute__((ext_vector_type(4)));

// ---- ws layout (float offsets) ----
#define W_ZS     0          // [4][16][2048] f32 partial Z
#define W_SS     131072     // [4][16][2048] f32 partial S1
#define W_OUTRED 262144     // [48][64] f32 (normalized)
#define W_TOPK   265216     // [48] int
#define W_U16    265280     // u16 region starts (16B aligned)
#define NPROJ 2097152
#define NW    786432
#define W_NEED_BYTES (265280*4 + 5*NPROJ*2 + 2*NW*2)

// ===========================================================================
__global__ void canary_kernel(float* __restrict__ out, float code, int n)
{
    int i = blockIdx.x * 256 + threadIdx.x;
    if (i < n) out[i] = (i == 0) ? code : 0.f;
}

__device__ __forceinline__ float rc_bf(u16 hi, u16 lo)
{
    return __uint_as_float(((unsigned)hi) << 16) + __uint_as_float(((unsigned)lo) << 16);
}

// ===========================================================================
// Stage 0: pre-split Wq,Wk,Wv -> hi/lo u16 arrays [3][512][512]
// ===========================================================================
__global__ __launch_bounds__(256) void wsplit_kernel(
    const float* __restrict__ Wq, const float* __restrict__ Wk,
    const float* __restrict__ Wv,
    u16* __restrict__ whi, u16* __restrict__ wlo)
{
    const int n1 = DMM * DMM;
    for (int i = blockIdx.x * 256 + threadIdx.x; i < 3 * n1; i += gridDim.x * 256) {
        const int z = i / n1, rem = i - z * n1;
        const float w = (z == 0 ? Wq : (z == 1 ? Wk : Wv))[rem];
        const unsigned u = __float_as_uint(w);
        const u16 hi = (u16)(u >> 16);
        const float hf = __uint_as_float(u & 0xFFFF0000u);
        whi[i] = hi;
        wlo[i] = (u16)(__float_as_uint(w - hf) >> 16);
    }
}

// ===========================================================================
// Stage 1 (MFMA): P = X @ W^T + b. Tile 128 rows x 64 cols, BK=32, 256 thr
// = 4 waves x 2 row-frags (32 rows/wave) -> B-tile LDS reads per output
// halved vs 64-row tile. LDS 30.7 KB. grid (32 row-tiles, 8 heads, 3).
// ===========================================================================
__global__ __launch_bounds__(256) void projM_kernel(
    const float* __restrict__ q, const float* __restrict__ k, const float* __restrict__ v,
    const u16* __restrict__ whi, const u16* __restrict__ wlo,
    const float* __restrict__ bq, const float* __restrict__ bk, const float* __restrict__ bv,
    u16* __restrict__ qhi, u16* __restrict__ qlo,
    u16* __restrict__ khi, u16* __restrict__ klo,
    u16* __restrict__ Vh)
{
    __shared__ u16 Ah[128][40], Al[128][40], Bh[64][40], Bl[64][40];

    const int z = blockIdx.z;
    const float *X, *Bi;
    if (z == 0)      { X = q; Bi = bq; }
    else if (z == 1) { X = k; Bi = bk; }
    else             { X = v; Bi = bv; }

    const int tid = threadIdx.x;
    const int m0 = blockIdx.x * 128;
    const int h  = blockIdx.y;
    const int n0 = h * 64;
    const int w  = tid >> 6;          // wave 0..3 -> rows w*32..+31
    const int lane = tid & 63;
    const int fr = lane & 15;
    const int kg = lane >> 4;
    const int kb = kg * 8;

    const int sr = tid >> 1;          // X staging row 0..127
    const int sk = (tid & 1) * 16;    // X staging k 0/16
    const int wr = tid >> 2;          // W staging row 0..63
    const int wk = (tid & 3) * 8;     // W staging k 0,8,16,24

    f32x4 acc[2][4];
#pragma unroll
    for (int t = 0; t < 2; ++t)
#pragma unroll
        for (int j = 0; j < 4; ++j) acc[t][j] = (f32x4){0.f, 0.f, 0.f, 0.f};

    for (int k0 = 0; k0 < DMM; k0 += 32) {
        __syncthreads();
        {
            // X rows: 16 floats -> split hi/lo
            const float* p = X + (size_t)(m0 + sr) * DMM + k0 + sk;
            float xv[16];
#pragma unroll
            for (int i4 = 0; i4 < 4; ++i4) {
                float4 a = *(const float4*)(p + i4 * 4);
                xv[i4*4+0]=a.x; xv[i4*4+1]=a.y; xv[i4*4+2]=a.z; xv[i4*4+3]=a.w;
            }
            unsigned hb[16], lb[16];
#pragma unroll
            for (int i = 0; i < 16; ++i) {
                unsigned u = __float_as_uint(xv[i]);
                hb[i] = u >> 16;
                float hf = __uint_as_float(u & 0xFFFF0000u);
                lb[i] = __float_as_uint(xv[i] - hf) >> 16;
            }
#pragma unroll
            for (int half = 0; half < 2; ++half) {
                uint4 H, L;
                H.x = hb[half*8+0]|(hb[half*8+1]<<16); H.y = hb[half*8+2]|(hb[half*8+3]<<16);
                H.z = hb[half*8+4]|(hb[half*8+5]<<16); H.w = hb[half*8+6]|(hb[half*8+7]<<16);
                L.x = lb[half*8+0]|(lb[half*8+1]<<16); L.y = lb[half*8+2]|(lb[half*8+3]<<16);
                L.z = lb[half*8+4]|(lb[half*8+5]<<16); L.w = lb[half*8+6]|(lb[half*8+7]<<16);
                *(uint4*)&Ah[sr][sk + half*8] = H;
                *(uint4*)&Al[sr][sk + half*8] = L;
            }

            // W rows: pre-split copy (8 u16 = 1 uint4 each)
            const size_t wi = ((size_t)z * DMM + n0 + wr) * DMM + k0 + wk;
            *(uint4*)&Bh[wr][wk] = *(const uint4*)(whi + wi);
            *(uint4*)&Bl[wr][wk] = *(const uint4*)(wlo + wi);
        }
        __syncthreads();

        bf16x8 ah[2], al[2];
#pragma unroll
        for (int t = 0; t < 2; ++t) {
            ah[t] = *(const bf16x8*)&Ah[w*32 + t*16 + fr][kb];
            al[t] = *(const bf16x8*)&Al[w*32 + t*16 + fr][kb];
        }
#pragma unroll
        for (int j = 0; j < 4; ++j) {
            bf16x8 bhf = *(const bf16x8*)&Bh[j*16 + fr][kb];
            bf16x8 blf = *(const bf16x8*)&Bl[j*16 + fr][kb];
#pragma unroll
            for (int t = 0; t < 2; ++t) {
                acc[t][j] = __builtin_amdgcn_mfma_f32_16x16x32_bf16(ah[t], bhf, acc[t][j], 0, 0, 0);
                acc[t][j] = __builtin_amdgcn_mfma_f32_16x16x32_bf16(ah[t], blf, acc[t][j], 0, 0, 0);
                acc[t][j] = __builtin_amdgcn_mfma_f32_16x16x32_bf16(al[t], bhf, acc[t][j], 0, 0, 0);
            }
        }
    }

    // epilogue: D frag col = lane&15, row = (lane>>4)*4 + r
#pragma unroll
    for (int t = 0; t < 2; ++t) {
#pragma unroll
        for (int j = 0; j < 4; ++j) {
            const int d = j*16 + fr;
            const float bias = Bi[n0 + d];
#pragma unroll
            for (int r = 0; r < 4; ++r) {
                const int row = m0 + w*32 + t*16 + kg*4 + r;
                const int bb  = row >> 11;
                const int tt  = row & 2047;
                const float val = acc[t][j][r] + bias;
                const size_t idx = ((size_t)(bb*HH + h) * TT + tt) * DH + d;
                const unsigned u = __float_as_uint(val);
                if (z == 2) {
                    Vh[idx] = (u16)((u + 0x7FFFu + ((u >> 16) & 1u)) >> 16);   // RNE
                } else {
                    const u16 hi = (u16)(u >> 16);
                    const float hf = __uint_as_float(u & 0xFFFF0000u);
                    const u16 lo = (u16)(__float_as_uint(val - hf) >> 16);
                    if (z == 0) { qhi[idx] = hi; qlo[idx] = lo; }
                    else        { khi[idx] = hi; klo[idx] = lo; }
                }
            }
        }
    }
}

// ===========================================================================
// Stage 2 (MFMA): partial (Z,S1) per q-row over a quarter of the K columns.
// grid (16 q-tiles of 128, 16 bh, 4 quarters), 256 thr = 4 waves x 2 row-
// frags -> K-tile LDS reads per output halved. LDS 19.4 KB.
// ===========================================================================
__global__ __launch_bounds__(256) void scoreM_kernel(
    const u16* __restrict__ qhi, const u16* __restrict__ qlo,
    const u16* __restrict__ khi, const u16* __restrict__ klo,
    float* __restrict__ zs, float* __restrict__ ss)
{
    __shared__ u16 Kh[64][76], Kl[64][76];

    const int qt = blockIdx.x, bh = blockIdx.y, zh = blockIdx.z;
    const int qr0 = qt * 128;
    const int tid = threadIdx.x;
    const int w  = tid >> 6;
    const int lane = tid & 63;
    const int fr = lane & 15;
    const int kg = lane >> 4;
    const int kb = kg * 8;

    // Q fragments direct to registers (2 row-frags per wave)
    bf16x8 qh0[2], qh1[2], ql0[2], ql1[2];
#pragma unroll
    for (int t = 0; t < 2; ++t) {
        const size_t qbase = ((size_t)bh*TT + qr0 + w*32 + t*16 + fr) * DH;
        qh0[t] = *(const bf16x8*)(qhi + qbase + kb);
        qh1[t] = *(const bf16x8*)(qhi + qbase + 32 + kb);
        ql0[t] = *(const bf16x8*)(qlo + qbase + kb);
        ql1[t] = *(const bf16x8*)(qlo + qbase + 32 + kb);
    }

    float zl[2][4], s1l[2][4];
#pragma unroll
    for (int t = 0; t < 2; ++t)
#pragma unroll
        for (int r = 0; r < 4; ++r) { zl[t][r] = 0.f; s1l[t][r] = 0.f; }

    const int c  = tid >> 2;          // 0..63
    const int dq = (tid & 3) * 16;    // 0,16,32,48

    for (int ct = zh * 8; ct < zh * 8 + 8; ++ct) {   // 64-col tiles
        __syncthreads();
        {
            const u16* sh = khi + ((size_t)bh*TT + ct*64 + c) * DH + dq;
            const u16* sl = klo + ((size_t)bh*TT + ct*64 + c) * DH + dq;
            *(uint4*)&Kh[c][dq]     = *(const uint4*)sh;
            *(uint4*)&Kh[c][dq + 8] = *(const uint4*)(sh + 8);
            *(uint4*)&Kl[c][dq]     = *(const uint4*)sl;
            *(uint4*)&Kl[c][dq + 8] = *(const uint4*)(sl + 8);
        }
        __syncthreads();

        f32x4 acc[2][4];
#pragma unroll
        for (int t = 0; t < 2; ++t)
#pragma unroll
            for (int j = 0; j < 4; ++j) acc[t][j] = (f32x4){0.f, 0.f, 0.f, 0.f};

#pragma unroll
        for (int j = 0; j < 4; ++j) {
            const bf16x8 b0h = *(const bf16x8*)&Kh[j*16 + fr][kb];
            const bf16x8 b0l = *(const bf16x8*)&Kl[j*16 + fr][kb];
            const bf16x8 b1h = *(const bf16x8*)&Kh[j*16 + fr][32 + kb];
            const bf16x8 b1l = *(const bf16x8*)&Kl[j*16 + fr][32 + kb];
#pragma unroll
            for (int t = 0; t < 2; ++t) {
                acc[t][j] = __builtin_amdgcn_mfma_f32_16x16x32_bf16(qh0[t], b0h, acc[t][j], 0, 0, 0);
                acc[t][j] = __builtin_amdgcn_mfma_f32_16x16x32_bf16(qh0[t], b0l, acc[t][j], 0, 0, 0);
                acc[t][j] = __builtin_amdgcn_mfma_f32_16x16x32_bf16(ql0[t], b0h, acc[t][j], 0, 0, 0);
                acc[t][j] = __builtin_amdgcn_mfma_f32_16x16x32_bf16(qh1[t], b1h, acc[t][j], 0, 0, 0);
                acc[t][j] = __builtin_amdgcn_mfma_f32_16x16x32_bf16(qh1[t], b1l, acc[t][j], 0, 0, 0);
                acc[t][j] = __builtin_amdgcn_mfma_f32_16x16x32_bf16(ql1[t], b1h, acc[t][j], 0, 0, 0);
            }
        }

#pragma unroll
        for (int t = 0; t < 2; ++t) {
#pragma unroll
            for (int j = 0; j < 4; ++j) {
#pragma unroll
                for (int r = 0; r < 4; ++r) {
                    float s = acc[t][j][r] * 0.125f;
                    float e = __expf(s);
                    zl[t][r]  += e;
                    s1l[t][r] += e * s;
                }
            }
        }
    }

    // butterfly over the 16 fr-lanes sharing kg
#pragma unroll
    for (int off = 1; off < 16; off <<= 1) {
#pragma unroll
        for (int t = 0; t < 2; ++t)
#pragma unroll
            for (int r = 0; r < 4; ++r) {
                zl[t][r]  += __shfl_xor(zl[t][r],  off, 64);
                s1l[t][r] += __shfl_xor(s1l[t][r], off, 64);
            }
    }

    if (fr == 0) {
#pragma unroll
        for (int t = 0; t < 2; ++t)
#pragma unroll
            for (int r = 0; r < 4; ++r) {
                const int row = qr0 + w*32 + t*16 + kg*4 + r;
                const size_t o = ((size_t)zh * NBH + bh) * TT + row;
                zs[o] = zl[t][r];
                ss[o] = s1l[t][r];
            }
    }
}

// ===========================================================================
// Stage 3: one block per (bh,u). Merge 4 partials -> KL, iterative argmax,
// then reduced attention with 256 threads. (verbatim R12)
// ===========================================================================
__global__ __launch_bounds__(256) void top3redM_kernel(
    const float* __restrict__ zs, const float* __restrict__ ss,
    const u16* __restrict__ qhi, const u16* __restrict__ qlo,
    const u16* __restrict__ khi, const u16* __restrict__ klo,
    const u16* __restrict__ Vh,
    int* __restrict__ topk, float* __restrict__ outred)
{
    __shared__ float kv[TT];
    __shared__ float pv[4];
    __shared__ int   pi[4];
    __shared__ int   tsel_sh;
    __shared__ float qs[DH];
    __shared__ float wbuf[TT];
    __shared__ float red4[4][DH];
    __shared__ float wz[4];

    const int bu = blockIdx.x;      // 0..47
    const int bh = bu / UU;
    const int uu = bu - bh * UU;
    const int tid = threadIdx.x;
    const int wv = tid >> 6;

    for (int i = tid; i < TT; i += 256) {
        float Z = 0.f, S = 0.f;
#pragma unroll
        for (int p = 0; p < 4; ++p) {
            const size_t o = ((size_t)p * NBH + bh) * TT + i;
            Z += zs[o];
            S += ss[o];
        }
        kv[i] = S / Z - logf(Z);
    }
    __syncthreads();
    for (int it = 0; it <= uu; ++it) {
        float bvv = -3e38f; int bi = TT;
        for (int i = tid; i < TT; i += 256) {
            float vv = kv[i];
            if (vv > bvv) { bvv = vv; bi = i; }
        }
#pragma unroll
        for (int off = 1; off < 64; off <<= 1) {
            float ov = __shfl_xor(bvv, off, 64);
            int   oi = __shfl_xor(bi, off, 64);
            if (ov > bvv || (ov == bvv && oi < bi)) { bvv = ov; bi = oi; }
        }
        if ((tid & 63) == 0) { pv[wv] = bvv; pi[wv] = bi; }
        __syncthreads();
        if (tid == 0) {
            float Bv = pv[0]; int Bi2 = pi[0];
#pragma unroll
            for (int w2 = 1; w2 < 4; ++w2) {
                if (pv[w2] > Bv || (pv[w2] == Bv && pi[w2] < Bi2)) { Bv = pv[w2]; Bi2 = pi[w2]; }
            }
            tsel_sh = Bi2;
            kv[Bi2] = -3e38f;
        }
        __syncthreads();
    }
    const int tsel = tsel_sh;
    if (tid == 0) topk[bu] = tsel;

    if (tid < DH) {
        const size_t qi = ((size_t)bh*TT + tsel) * DH + tid;
        qs[tid] = rc_bf(qhi[qi], qlo[qi]);
    }
    __syncthreads();

    float zp = 0.f;
    for (int cc = tid; cc < TT; cc += 256) {
        const u16* kh  = khi + ((size_t)bh*TT + cc) * DH;
        const u16* kl_ = klo + ((size_t)bh*TT + cc) * DH;
        float s = 0.f;
#pragma unroll
        for (int d8 = 0; d8 < DH; d8 += 8) {
            uint4 H = *(const uint4*)(kh + d8);
            uint4 L = *(const uint4*)(kl_ + d8);
            const unsigned hw[4] = {H.x, H.y, H.z, H.w};
            const unsigned lw[4] = {L.x, L.y, L.z, L.w};
#pragma unroll
            for (int i = 0; i < 4; ++i) {
                float k0 = __uint_as_float(hw[i] << 16) + __uint_as_float(lw[i] << 16);
                float k1 = __uint_as_float(hw[i] & 0xFFFF0000u) + __uint_as_float(lw[i] & 0xFFFF0000u);
                s += qs[d8 + i*2]     * k0;
                s += qs[d8 + i*2 + 1] * k1;
            }
        }
        s *= 0.125f;
        s = fminf(fmaxf(s, -10000.f), 10000.f);
        float e = __expf(s);
        wbuf[cc] = e;
        zp += e;
    }
#pragma unroll
    for (int off = 1; off < 64; off <<= 1) zp += __shfl_xor(zp, off, 64);
    if ((tid & 63) == 0) wz[wv] = zp;
    __syncthreads();
    const float Z = wz[0] + wz[1] + wz[2] + wz[3];

    const int d = tid & 63, cq = tid >> 6;
    float o = 0.f;
    for (int cc = cq * 512; cc < cq * 512 + 512; ++cc) {
        const u16 vb = Vh[((size_t)bh*TT + cc) * DH + d];
        o += wbuf[cc] * __uint_as_float(((unsigned)vb) << 16);
    }
    red4[cq][d] = o;
    __syncthreads();
    if (tid < DH)
        outred[bu*DH + tid] =
            (red4[0][tid] + red4[1][tid] + red4[2][tid] + red4[3][tid]) / Z;
}

// ===========================================================================
// Stage 4: out[b,t,:] = bo + sum_{(h,u): topk==t} outred @ Wo[:,h*64..]^T
// (verbatim R12)
// ===========================================================================
__global__ __launch_bounds__(256) void outU_kernel(
    const float* __restrict__ outred, const int* __restrict__ topk,
    const float* __restrict__ Wo, const float* __restrict__ bo,
    float* __restrict__ out)
{
    const int blk = blockIdx.x;
    const int b   = blk >> 11;
    const int t   = blk & 2047;
    const int tid = threadIdx.x;
    float acc0 = bo[tid];
    float acc1 = bo[tid + 256];
    for (int h = 0; h < HH; ++h) {
#pragma unroll
        for (int u = 0; u < UU; ++u) {
            const int idx = (b*HH + h)*UU + u;
            if (topk[idx] == t) {
                const float* r  = outred + (size_t)idx * DH;
                const float* w0 = Wo + (size_t)tid * DMM + h*DH;
                const float* w1 = Wo + (size_t)(tid + 256) * DMM + h*DH;
#pragma unroll
                for (int dd = 0; dd < DH; ++dd) {
                    const float rv = r[dd];
                    acc0 += rv * w0[dd];
                    acc1 += rv * w1[dd];
                }
            }
        }
    }
    out[(size_t)blk * DMM + tid]       = acc0;
    out[(size_t)blk * DMM + tid + 256] = acc1;
}

// ===========================================================================
extern "C" void kernel_launch(void* const* d_in, const int* in_sizes, int n_in,
                              void* d_out, int out_size, void* d_ws, size_t ws_size,
                              hipStream_t stream)
{
    float* out = (float*)d_out;
    const int nblk = (out_size + 255) / 256;

    if (n_in != 11) {
        canary_kernel<<<nblk, 256, 0, stream>>>(out, 9216.f + 8.f * (float)n_in, out_size);
        return;
    }
    const int s0 = in_sizes[0];
    int mode = -1;
    if ((s0 == 2097152 || s0 == 8388608) &&
        (in_sizes[4] == 512 || in_sizes[4] == 2048)) mode = 0;
    else if ((s0 == 262144 || s0 == 1048576) &&
             (in_sizes[8] == 2097152 || in_sizes[8] == 8388608)) mode = 1;
    if (mode < 0) {
        canary_kernel<<<nblk, 256, 0, stream>>>(out, 8192.f, out_size);
        return;
    }
    if (ws_size < (size_t)W_NEED_BYTES) {
        canary_kernel<<<nblk, 256, 0, stream>>>(out, 5120.f, out_size);
        return;
    }

    const float *q, *k, *v, *Wq, *bq, *Wk, *bk, *Wv, *bv, *Wo, *bo;
    if (mode == 0) {
        q  = (const float*)d_in[0];  k  = (const float*)d_in[1];
        v  = (const float*)d_in[2];  Wq = (const float*)d_in[3];
        bq = (const float*)d_in[4];  Wk = (const float*)d_in[5];
        bk = (const float*)d_in[6];  Wv = (const float*)d_in[7];
        bv = (const float*)d_in[8];  Wo = (const float*)d_in[9];
        bo = (const float*)d_in[10];
    } else {
        Wk = (const float*)d_in[0];  Wo = (const float*)d_in[1];
        Wq = (const float*)d_in[2];  Wv = (const float*)d_in[3];
        bk = (const float*)d_in[4];  bo = (const float*)d_in[5];
        bq = (const float*)d_in[6];  bv = (const float*)d_in[7];
        k  = (const float*)d_in[8];  q  = (const float*)d_in[9];
        v  = (const float*)d_in[10];
    }

    float* ws     = (float*)d_ws;
    float* zs     = ws + W_ZS;
    float* ss     = ws + W_SS;
    float* outred = ws + W_OUTRED;
    int*   topk   = (int*)(ws + W_TOPK);
    u16*   qhi    = (u16*)(ws + W_U16);
    u16*   qlo    = qhi + (size_t)NPROJ;
    u16*   khi    = qlo + (size_t)NPROJ;
    u16*   klo    = khi + (size_t)NPROJ;
    u16*   Vh     = klo + (size_t)NPROJ;
    u16*   whi    = Vh  + (size_t)NPROJ;
    u16*   wlo    = whi + (size_t)NW;

    wsplit_kernel<<<1024, 256, 0, stream>>>(Wq, Wk, Wv, whi, wlo);
    projM_kernel<<<dim3(32, 8, 3), 256, 0, stream>>>(q, k, v, whi, wlo, bq, bk, bv,
                                                     qhi, qlo, khi, klo, Vh);
    scoreM_kernel<<<dim3(16, 16, 4), 256, 0, stream>>>(qhi, qlo, khi, klo, zs, ss);
    top3redM_kernel<<<48, 256, 0, stream>>>(zs, ss, qhi, qlo, khi, klo, Vh, topk, outred);
    outU_kernel<<<4096, 256, 0, stream>>>(outred, topk, Wo, bo, out);
}

// Round 16
// 109.854 us; speedup vs baseline: 2.5296x; 1.2141x over previous
//
#include <hip/hip_runtime.h>
#include <hip/hip_bf16.h>

#define TT 2048
#define DMM 512
#define HH 8
#define DH 64
#define NBH 16   // B*H
#define UU 3     // int(0.4*ln(2048)) = 3
#define NPARTS 8

typedef unsigned short u16;
typedef short bf16x8 __attribute__((ext_vector_type(8)));
typedef float f32x4 __attribute__((ext_vector_type(4)));

// ---- ws layout (float offsets) ----
#define W_ZS     0          // [4][16][2048] f32 partial Z (scoreM)
#define W_SS     131072     // [4][16][2048] f32 partial S1
#define W_ZP     262144     // [48][8] f32 reduced-attn partial Z
#define W_OP     262528     // [48][8][64] f32 reduced-attn partial O
#define W_TOPK   287104     // [48] int
#define W_U16    287168     // u16 region starts (16B aligned)
#define NPROJ 2097152
#define NW    786432
#define W_NEED_BYTES (287168*4 + 5*NPROJ*2 + 2*NW*2)

// ===========================================================================
__global__ void canary_kernel(float* __restrict__ out, float code, int n)
{
    int i = blockIdx.x * 256 + threadIdx.x;
    if (i < n) out[i] = (i == 0) ? code : 0.f;
}

__device__ __forceinline__ float rc_bf(u16 hi, u16 lo)
{
    return __uint_as_float(((unsigned)hi) << 16) + __uint_as_float(((unsigned)lo) << 16);
}

// ===========================================================================
// Stage 0: pre-split Wq,Wk,Wv -> hi/lo u16 arrays [3][512][512]
// ===========================================================================
__global__ __launch_bounds__(256) void wsplit_kernel(
    const float* __restrict__ Wq, const float* __restrict__ Wk,
    const float* __restrict__ Wv,
    u16* __restrict__ whi, u16* __restrict__ wlo)
{
    const int n1 = DMM * DMM;
    for (int i = blockIdx.x * 256 + threadIdx.x; i < 3 * n1; i += gridDim.x * 256) {
        const int z = i / n1, rem = i - z * n1;
        const float w = (z == 0 ? Wq : (z == 1 ? Wk : Wv))[rem];
        const unsigned u = __float_as_uint(w);
        const u16 hi = (u16)(u >> 16);
        const float hf = __uint_as_float(u & 0xFFFF0000u);
        whi[i] = hi;
        wlo[i] = (u16)(__float_as_uint(w - hf) >> 16);
    }
}

// ===========================================================================
// Stage 1 (MFMA): P = X @ W^T + b. Tile 128 rows x 64 cols, BK=32, 256 thr
// = 4 waves x 2 row-frags. LDS 30.7 KB. grid (32 row-tiles, 8 heads, 3).
// (verbatim R15)
// ===========================================================================
__global__ __launch_bounds__(256) void projM_kernel(
    const float* __restrict__ q, const float* __restrict__ k, const float* __restrict__ v,
    const u16* __restrict__ whi, const u16* __restrict__ wlo,
    const float* __restrict__ bq, const float* __restrict__ bk, const float* __restrict__ bv,
    u16* __restrict__ qhi, u16* __restrict__ qlo,
    u16* __restrict__ khi, u16* __restrict__ klo,
    u16* __restrict__ Vh)
{
    __shared__ u16 Ah[128][40], Al[128][40], Bh[64][40], Bl[64][40];

    const int z = blockIdx.z;
    const float *X, *Bi;
    if (z == 0)      { X = q; Bi = bq; }
    else if (z == 1) { X = k; Bi = bk; }
    else             { X = v; Bi = bv; }

    const int tid = threadIdx.x;
    const int m0 = blockIdx.x * 128;
    const int h  = blockIdx.y;
    const int n0 = h * 64;
    const int w  = tid >> 6;
    const int lane = tid & 63;
    const int fr = lane & 15;
    const int kg = lane >> 4;
    const int kb = kg * 8;

    const int sr = tid >> 1;
    const int sk = (tid & 1) * 16;
    const int wr = tid >> 2;
    const int wk = (tid & 3) * 8;

    f32x4 acc[2][4];
#pragma unroll
    for (int t = 0; t < 2; ++t)
#pragma unroll
        for (int j = 0; j < 4; ++j) acc[t][j] = (f32x4){0.f, 0.f, 0.f, 0.f};

    for (int k0 = 0; k0 < DMM; k0 += 32) {
        __syncthreads();
        {
            const float* p = X + (size_t)(m0 + sr) * DMM + k0 + sk;
            float xv[16];
#pragma unroll
            for (int i4 = 0; i4 < 4; ++i4) {
                float4 a = *(const float4*)(p + i4 * 4);
                xv[i4*4+0]=a.x; xv[i4*4+1]=a.y; xv[i4*4+2]=a.z; xv[i4*4+3]=a.w;
            }
            unsigned hb[16], lb[16];
#pragma unroll
            for (int i = 0; i < 16; ++i) {
                unsigned u = __float_as_uint(xv[i]);
                hb[i] = u >> 16;
                float hf = __uint_as_float(u & 0xFFFF0000u);
                lb[i] = __float_as_uint(xv[i] - hf) >> 16;
            }
#pragma unroll
            for (int half = 0; half < 2; ++half) {
                uint4 H, L;
                H.x = hb[half*8+0]|(hb[half*8+1]<<16); H.y = hb[half*8+2]|(hb[half*8+3]<<16);
                H.z = hb[half*8+4]|(hb[half*8+5]<<16); H.w = hb[half*8+6]|(hb[half*8+7]<<16);
                L.x = lb[half*8+0]|(lb[half*8+1]<<16); L.y = lb[half*8+2]|(lb[half*8+3]<<16);
                L.z = lb[half*8+4]|(lb[half*8+5]<<16); L.w = lb[half*8+6]|(lb[half*8+7]<<16);
                *(uint4*)&Ah[sr][sk + half*8] = H;
                *(uint4*)&Al[sr][sk + half*8] = L;
            }

            const size_t wi = ((size_t)z * DMM + n0 + wr) * DMM + k0 + wk;
            *(uint4*)&Bh[wr][wk] = *(const uint4*)(whi + wi);
            *(uint4*)&Bl[wr][wk] = *(const uint4*)(wlo + wi);
        }
        __syncthreads();

        bf16x8 ah[2], al[2];
#pragma unroll
        for (int t = 0; t < 2; ++t) {
            ah[t] = *(const bf16x8*)&Ah[w*32 + t*16 + fr][kb];
            al[t] = *(const bf16x8*)&Al[w*32 + t*16 + fr][kb];
        }
#pragma unroll
        for (int j = 0; j < 4; ++j) {
            bf16x8 bhf = *(const bf16x8*)&Bh[j*16 + fr][kb];
            bf16x8 blf = *(const bf16x8*)&Bl[j*16 + fr][kb];
#pragma unroll
            for (int t = 0; t < 2; ++t) {
                acc[t][j] = __builtin_amdgcn_mfma_f32_16x16x32_bf16(ah[t], bhf, acc[t][j], 0, 0, 0);
                acc[t][j] = __builtin_amdgcn_mfma_f32_16x16x32_bf16(ah[t], blf, acc[t][j], 0, 0, 0);
                acc[t][j] = __builtin_amdgcn_mfma_f32_16x16x32_bf16(al[t], bhf, acc[t][j], 0, 0, 0);
            }
        }
    }

#pragma unroll
    for (int t = 0; t < 2; ++t) {
#pragma unroll
        for (int j = 0; j < 4; ++j) {
            const int d = j*16 + fr;
            const float bias = Bi[n0 + d];
#pragma unroll
            for (int r = 0; r < 4; ++r) {
                const int row = m0 + w*32 + t*16 + kg*4 + r;
                const int bb  = row >> 11;
                const int tt  = row & 2047;
                const float val = acc[t][j][r] + bias;
                const size_t idx = ((size_t)(bb*HH + h) * TT + tt) * DH + d;
                const unsigned u = __float_as_uint(val);
                if (z == 2) {
                    Vh[idx] = (u16)((u + 0x7FFFu + ((u >> 16) & 1u)) >> 16);   // RNE
                } else {
                    const u16 hi = (u16)(u >> 16);
                    const float hf = __uint_as_float(u & 0xFFFF0000u);
                    const u16 lo = (u16)(__float_as_uint(val - hf) >> 16);
                    if (z == 0) { qhi[idx] = hi; qlo[idx] = lo; }
                    else        { khi[idx] = hi; klo[idx] = lo; }
                }
            }
        }
    }
}

// ===========================================================================
// Stage 2 (MFMA): partial (Z,S1) per q-row over a quarter of the K columns.
// grid (16 q-tiles of 128, 16 bh, 4 quarters), 256 thr. (verbatim R15)
// ===========================================================================
__global__ __launch_bounds__(256) void scoreM_kernel(
    const u16* __restrict__ qhi, const u16* __restrict__ qlo,
    const u16* __restrict__ khi, const u16* __restrict__ klo,
    float* __restrict__ zs, float* __restrict__ ss)
{
    __shared__ u16 Kh[64][76], Kl[64][76];

    const int qt = blockIdx.x, bh = blockIdx.y, zh = blockIdx.z;
    const int qr0 = qt * 128;
    const int tid = threadIdx.x;
    const int w  = tid >> 6;
    const int lane = tid & 63;
    const int fr = lane & 15;
    const int kg = lane >> 4;
    const int kb = kg * 8;

    bf16x8 qh0[2], qh1[2], ql0[2], ql1[2];
#pragma unroll
    for (int t = 0; t < 2; ++t) {
        const size_t qbase = ((size_t)bh*TT + qr0 + w*32 + t*16 + fr) * DH;
        qh0[t] = *(const bf16x8*)(qhi + qbase + kb);
        qh1[t] = *(const bf16x8*)(qhi + qbase + 32 + kb);
        ql0[t] = *(const bf16x8*)(qlo + qbase + kb);
        ql1[t] = *(const bf16x8*)(qlo + qbase + 32 + kb);
    }

    float zl[2][4], s1l[2][4];
#pragma unroll
    for (int t = 0; t < 2; ++t)
#pragma unroll
        for (int r = 0; r < 4; ++r) { zl[t][r] = 0.f; s1l[t][r] = 0.f; }

    const int c  = tid >> 2;
    const int dq = (tid & 3) * 16;

    for (int ct = zh * 8; ct < zh * 8 + 8; ++ct) {
        __syncthreads();
        {
            const u16* sh = khi + ((size_t)bh*TT + ct*64 + c) * DH + dq;
            const u16* sl = klo + ((size_t)bh*TT + ct*64 + c) * DH + dq;
            *(uint4*)&Kh[c][dq]     = *(const uint4*)sh;
            *(uint4*)&Kh[c][dq + 8] = *(const uint4*)(sh + 8);
            *(uint4*)&Kl[c][dq]     = *(const uint4*)sl;
            *(uint4*)&Kl[c][dq + 8] = *(const uint4*)(sl + 8);
        }
        __syncthreads();

        f32x4 acc[2][4];
#pragma unroll
        for (int t = 0; t < 2; ++t)
#pragma unroll
            for (int j = 0; j < 4; ++j) acc[t][j] = (f32x4){0.f, 0.f, 0.f, 0.f};

#pragma unroll
        for (int j = 0; j < 4; ++j) {
            const bf16x8 b0h = *(const bf16x8*)&Kh[j*16 + fr][kb];
            const bf16x8 b0l = *(const bf16x8*)&Kl[j*16 + fr][kb];
            const bf16x8 b1h = *(const bf16x8*)&Kh[j*16 + fr][32 + kb];
            const bf16x8 b1l = *(const bf16x8*)&Kl[j*16 + fr][32 + kb];
#pragma unroll
            for (int t = 0; t < 2; ++t) {
                acc[t][j] = __builtin_amdgcn_mfma_f32_16x16x32_bf16(qh0[t], b0h, acc[t][j], 0, 0, 0);
                acc[t][j] = __builtin_amdgcn_mfma_f32_16x16x32_bf16(qh0[t], b0l, acc[t][j], 0, 0, 0);
                acc[t][j] = __builtin_amdgcn_mfma_f32_16x16x32_bf16(ql0[t], b0h, acc[t][j], 0, 0, 0);
                acc[t][j] = __builtin_amdgcn_mfma_f32_16x16x32_bf16(qh1[t], b1h, acc[t][j], 0, 0, 0);
                acc[t][j] = __builtin_amdgcn_mfma_f32_16x16x32_bf16(qh1[t], b1l, acc[t][j], 0, 0, 0);
                acc[t][j] = __builtin_amdgcn_mfma_f32_16x16x32_bf16(ql1[t], b1h, acc[t][j], 0, 0, 0);
            }
        }

#pragma unroll
        for (int t = 0; t < 2; ++t) {
#pragma unroll
            for (int j = 0; j < 4; ++j) {
#pragma unroll
                for (int r = 0; r < 4; ++r) {
                    float s = acc[t][j][r] * 0.125f;
                    float e = __expf(s);
                    zl[t][r]  += e;
                    s1l[t][r] += e * s;
                }
            }
        }
    }

#pragma unroll
    for (int off = 1; off < 16; off <<= 1) {
#pragma unroll
        for (int t = 0; t < 2; ++t)
#pragma unroll
            for (int r = 0; r < 4; ++r) {
                zl[t][r]  += __shfl_xor(zl[t][r],  off, 64);
                s1l[t][r] += __shfl_xor(s1l[t][r], off, 64);
            }
    }

    if (fr == 0) {
#pragma unroll
        for (int t = 0; t < 2; ++t)
#pragma unroll
            for (int r = 0; r < 4; ++r) {
                const int row = qr0 + w*32 + t*16 + kg*4 + r;
                const size_t o = ((size_t)zh * NBH + bh) * TT + row;
                zs[o] = zl[t][r];
                ss[o] = s1l[t][r];
            }
    }
}

// ===========================================================================
// Stage 3: grid (48 bu, 8 col-parts). Each block: merge scoreM partials ->
// KL, iterative argmax (redundant per part, deterministic identical), then
// reduced-attention PARTIAL over its 256 columns. No atomics.
// ===========================================================================
__global__ __launch_bounds__(256) void top3redM_kernel(
    const float* __restrict__ zs, const float* __restrict__ ss,
    const u16* __restrict__ qhi, const u16* __restrict__ qlo,
    const u16* __restrict__ khi, const u16* __restrict__ klo,
    const u16* __restrict__ Vh,
    int* __restrict__ topk, float* __restrict__ zp_out, float* __restrict__ op_out)
{
    __shared__ float kv[TT];
    __shared__ float pv[4];
    __shared__ int   pi[4];
    __shared__ int   tsel_sh;
    __shared__ float qs[DH];
    __shared__ float wbuf[256];
    __shared__ float red4[4][DH];
    __shared__ float wz[4];

    const int bu = blockIdx.x;      // 0..47
    const int part = blockIdx.y;    // 0..7
    const int bh = bu / UU;
    const int uu = bu - bh * UU;
    const int tid = threadIdx.x;
    const int wv = tid >> 6;

    // ---- phase A: KL from partials + iterative argmax (ties -> low idx) ----
    for (int i = tid; i < TT; i += 256) {
        float Z = 0.f, S = 0.f;
#pragma unroll
        for (int p = 0; p < 4; ++p) {
            const size_t o = ((size_t)p * NBH + bh) * TT + i;
            Z += zs[o];
            S += ss[o];
        }
        kv[i] = S / Z - logf(Z);   // -log_u constant: argmax-invariant
    }
    __syncthreads();
    for (int it = 0; it <= uu; ++it) {
        float bvv = -3e38f; int bi = TT;
        for (int i = tid; i < TT; i += 256) {
            float vv = kv[i];
            if (vv > bvv) { bvv = vv; bi = i; }
        }
#pragma unroll
        for (int off = 1; off < 64; off <<= 1) {
            float ov = __shfl_xor(bvv, off, 64);
            int   oi = __shfl_xor(bi, off, 64);
            if (ov > bvv || (ov == bvv && oi < bi)) { bvv = ov; bi = oi; }
        }
        if ((tid & 63) == 0) { pv[wv] = bvv; pi[wv] = bi; }
        __syncthreads();
        if (tid == 0) {
            float Bv = pv[0]; int Bi2 = pi[0];
#pragma unroll
            for (int w2 = 1; w2 < 4; ++w2) {
                if (pv[w2] > Bv || (pv[w2] == Bv && pi[w2] < Bi2)) { Bv = pv[w2]; Bi2 = pi[w2]; }
            }
            tsel_sh = Bi2;
            kv[Bi2] = -3e38f;
        }
        __syncthreads();
    }
    const int tsel = tsel_sh;
    if (tid == 0 && part == 0) topk[bu] = tsel;

    // ---- phase B: reduced-attention partial over cols [part*256, +256) ----
    if (tid < DH) {
        const size_t qi = ((size_t)bh*TT + tsel) * DH + tid;
        qs[tid] = rc_bf(qhi[qi], qlo[qi]);
    }
    __syncthreads();

    const int c0 = part * 256;
    const int cc = c0 + tid;                       // one column per thread
    {
        const u16* kh  = khi + ((size_t)bh*TT + cc) * DH;
        const u16* kl_ = klo + ((size_t)bh*TT + cc) * DH;
        float s = 0.f;
#pragma unroll
        for (int d8 = 0; d8 < DH; d8 += 8) {
            uint4 H = *(const uint4*)(kh + d8);
            uint4 L = *(const uint4*)(kl_ + d8);
            const unsigned hw[4] = {H.x, H.y, H.z, H.w};
            const unsigned lw[4] = {L.x, L.y, L.z, L.w};
#pragma unroll
            for (int i = 0; i < 4; ++i) {
                float k0 = __uint_as_float(hw[i] << 16) + __uint_as_float(lw[i] << 16);
                float k1 = __uint_as_float(hw[i] & 0xFFFF0000u) + __uint_as_float(lw[i] & 0xFFFF0000u);
                s += qs[d8 + i*2]     * k0;
                s += qs[d8 + i*2 + 1] * k1;
            }
        }
        s *= 0.125f;
        s = fminf(fmaxf(s, -10000.f), 10000.f);
        float e = __expf(s);
        wbuf[tid] = e;
        float zp = e;
#pragma unroll
        for (int off = 1; off < 64; off <<= 1) zp += __shfl_xor(zp, off, 64);
        if ((tid & 63) == 0) wz[wv] = zp;
    }
    __syncthreads();
    if (tid == 0) zp_out[bu*NPARTS + part] = wz[0] + wz[1] + wz[2] + wz[3];

    const int d = tid & 63, cq = tid >> 6;
    float o = 0.f;
#pragma unroll
    for (int i = 0; i < 64; ++i) {
        const int ii = cq * 64 + i;
        const u16 vb = Vh[((size_t)bh*TT + c0 + ii) * DH + d];
        o += wbuf[ii] * __uint_as_float(((unsigned)vb) << 16);
    }
    red4[cq][d] = o;
    __syncthreads();
    if (tid < DH)
        op_out[(size_t)(bu*NPARTS + part) * DH + tid] =
            red4[0][tid] + red4[1][tid] + red4[2][tid] + red4[3][tid];
}

// ===========================================================================
// Stage 4: out[b,t,:] = bo + sum_{(h,u): topk==t} (merge 8 partials) @ Wo^T
// ===========================================================================
__global__ __launch_bounds__(256) void outU_kernel(
    const float* __restrict__ zp, const float* __restrict__ op,
    const int* __restrict__ topk,
    const float* __restrict__ Wo, const float* __restrict__ bo,
    float* __restrict__ out)
{
    const int blk = blockIdx.x;
    const int b   = blk >> 11;
    const int t   = blk & 2047;
    const int tid = threadIdx.x;
    float acc0 = bo[tid];
    float acc1 = bo[tid + 256];
    for (int h = 0; h < HH; ++h) {
#pragma unroll
        for (int u = 0; u < UU; ++u) {
            const int idx = (b*HH + h)*UU + u;
            if (topk[idx] == t) {
                float Z = 0.f;
#pragma unroll
                for (int p = 0; p < NPARTS; ++p) Z += zp[idx*NPARTS + p];
                const float invz = 1.0f / Z;
                const float* ob = op + (size_t)idx * NPARTS * DH;
                const float* w0 = Wo + (size_t)tid * DMM + h*DH;
                const float* w1 = Wo + (size_t)(tid + 256) * DMM + h*DH;
#pragma unroll
                for (int dd = 0; dd < DH; ++dd) {
                    float rv = 0.f;
#pragma unroll
                    for (int p = 0; p < NPARTS; ++p) rv += ob[p*DH + dd];
                    rv *= invz;
                    acc0 += rv * w0[dd];
                    acc1 += rv * w1[dd];
                }
            }
        }
    }
    out[(size_t)blk * DMM + tid]       = acc0;
    out[(size_t)blk * DMM + tid + 256] = acc1;
}

// ===========================================================================
extern "C" void kernel_launch(void* const* d_in, const int* in_sizes, int n_in,
                              void* d_out, int out_size, void* d_ws, size_t ws_size,
                              hipStream_t stream)
{
    float* out = (float*)d_out;
    const int nblk = (out_size + 255) / 256;

    if (n_in != 11) {
        canary_kernel<<<nblk, 256, 0, stream>>>(out, 9216.f + 8.f * (float)n_in, out_size);
        return;
    }
    const int s0 = in_sizes[0];
    int mode = -1;
    if ((s0 == 2097152 || s0 == 8388608) &&
        (in_sizes[4] == 512 || in_sizes[4] == 2048)) mode = 0;
    else if ((s0 == 262144 || s0 == 1048576) &&
             (in_sizes[8] == 2097152 || in_sizes[8] == 8388608)) mode = 1;
    if (mode < 0) {
        canary_kernel<<<nblk, 256, 0, stream>>>(out, 8192.f, out_size);
        return;
    }
    if (ws_size < (size_t)W_NEED_BYTES) {
        canary_kernel<<<nblk, 256, 0, stream>>>(out, 5120.f, out_size);
        return;
    }

    const float *q, *k, *v, *Wq, *bq, *Wk, *bk, *Wv, *bv, *Wo, *bo;
    if (mode == 0) {
        q  = (const float*)d_in[0];  k  = (const float*)d_in[1];
        v  = (const float*)d_in[2];  Wq = (const float*)d_in[3];
        bq = (const float*)d_in[4];  Wk = (const float*)d_in[5];
        bk = (const float*)d_in[6];  Wv = (const float*)d_in[7];
        bv = (const float*)d_in[8];  Wo = (const float*)d_in[9];
        bo = (const float*)d_in[10];
    } else {
        Wk = (const float*)d_in[0];  Wo = (const float*)d_in[1];
        Wq = (const float*)d_in[2];  Wv = (const float*)d_in[3];
        bk = (const float*)d_in[4];  bo = (const float*)d_in[5];
        bq = (const float*)d_in[6];  bv = (const float*)d_in[7];
        k  = (const float*)d_in[8];  q  = (const float*)d_in[9];
        v  = (const float*)d_in[10];
    }

    float* ws     = (float*)d_ws;
    float* zs     = ws + W_ZS;
    float* ss     = ws + W_SS;
    float* zp     = ws + W_ZP;
    float* op     = ws + W_OP;
    int*   topk   = (int*)(ws + W_TOPK);
    u16*   qhi    = (u16*)(ws + W_U16);
    u16*   qlo    = qhi + (size_t)NPROJ;
    u16*   khi    = qlo + (size_t)NPROJ;
    u16*   klo    = khi + (size_t)NPROJ;
    u16*   Vh     = klo + (size_t)NPROJ;
    u16*   whi    = Vh  + (size_t)NPROJ;
    u16*   wlo    = whi + (size_t)NW;

    wsplit_kernel<<<1024, 256, 0, stream>>>(Wq, Wk, Wv, whi, wlo);
    projM_kernel<<<dim3(32, 8, 3), 256, 0, stream>>>(q, k, v, whi, wlo, bq, bk, bv,
                                                     qhi, qlo, khi, klo, Vh);
    scoreM_kernel<<<dim3(16, 16, 4), 256, 0, stream>>>(qhi, qlo, khi, klo, zs, ss);
    top3redM_kernel<<<dim3(48, NPARTS), 256, 0, stream>>>(zs, ss, qhi, qlo, khi, klo, Vh,
                                                          topk, zp, op);
    outU_kernel<<<4096, 256, 0, stream>>>(zp, op, topk, Wo, bo, out);
}